// Round 1
// baseline (83.935 us; speedup 1.0000x reference)
//
#include <hip/hip_runtime.h>
#include <hip/hip_bf16.h>

#define NB 384
#define ND 512

// ---------------- Kernel 1: scores = emb @ emb.T (f32) ----------------
// 32x32 output tile per block, BK=64, 2x2 per-thread register tile.
__global__ __launch_bounds__(256) void gemm_scores(const float* __restrict__ emb,
                                                   float* __restrict__ s) {
    __shared__ float As[32][65];   // +1 pad -> bank-conflict-free column reads
    __shared__ float Bs[32][65];
    const int tid = threadIdx.x;
    const int tx = tid & 15, ty = tid >> 4;
    const int i0 = blockIdx.y * 32, j0 = blockIdx.x * 32;
    float acc00 = 0.f, acc01 = 0.f, acc10 = 0.f, acc11 = 0.f;

    for (int k0 = 0; k0 < ND; k0 += 64) {
        // stage 32 rows x 64 cols of A and B (2048 f32 each) via float4
#pragma unroll
        for (int p = 0; p < 2; ++p) {
            int idx = tid + 256 * p;
            int r = idx >> 4;           // 0..31
            int c = (idx & 15) << 2;    // 0..60
            float4 av = *reinterpret_cast<const float4*>(emb + (i0 + r) * ND + k0 + c);
            As[r][c] = av.x; As[r][c + 1] = av.y; As[r][c + 2] = av.z; As[r][c + 3] = av.w;
            float4 bv = *reinterpret_cast<const float4*>(emb + (j0 + r) * ND + k0 + c);
            Bs[r][c] = bv.x; Bs[r][c + 1] = bv.y; Bs[r][c + 2] = bv.z; Bs[r][c + 3] = bv.w;
        }
        __syncthreads();
#pragma unroll 8
        for (int kk = 0; kk < 64; ++kk) {
            float a0 = As[2 * ty][kk], a1 = As[2 * ty + 1][kk];
            float b0 = Bs[2 * tx][kk], b1 = Bs[2 * tx + 1][kk];
            acc00 = fmaf(a0, b0, acc00); acc01 = fmaf(a0, b1, acc01);
            acc10 = fmaf(a1, b0, acc10); acc11 = fmaf(a1, b1, acc11);
        }
        __syncthreads();
    }
    const int i = i0 + 2 * ty, j = j0 + 2 * tx;
    s[i * NB + j]           = acc00; s[i * NB + j + 1]       = acc01;
    s[(i + 1) * NB + j]     = acc10; s[(i + 1) * NB + j + 1] = acc11;
}

// ---------------- Kernel 2: main B^3 pass ----------------
// grid (6, 384): blockIdx.y = b, blockIdx.x = 64-wide i-chunk.
// 256 threads = 4 waves; each wave owns 16 i's; 64 lanes sweep j (6 steps).
__global__ __launch_bounds__(256) void hap_main(const float* __restrict__ s,
                                                const int* __restrict__ labels,
                                                float* __restrict__ block_out) {
    __shared__ float s_row[NB];
    __shared__ float t_row[NB];
    __shared__ float red[256];
    __shared__ float qlds[4];
    __shared__ float relsum_sh;

    const int tid = threadIdx.x;
    const int b = blockIdx.y;
    const int chunk = blockIdx.x;   // 0..5

    const int l0 = labels[b * 3 + 0];
    const int l1 = labels[b * 3 + 1];
    const int l2 = labels[b * 3 + 2];

    float part = 0.f;
    for (int j = tid; j < NB; j += 256) {
        float t = (float)((labels[j * 3 + 0] == l0) +
                          (labels[j * 3 + 1] == l1) +
                          (labels[j * 3 + 2] == l2));
        t_row[j] = t;
        s_row[j] = s[b * NB + j];
        part += t;
    }
    red[tid] = part;
    __syncthreads();
    for (int sft = 128; sft > 0; sft >>= 1) {
        if (tid < sft) red[tid] += red[tid + sft];
        __syncthreads();
    }
    if (tid == 0) relsum_sh = red[0] * (1.f / 3.f);
    __syncthreads();
    const float relsum = relsum_sh;

    const int wave = tid >> 6, lane = tid & 63;
    const int ibase = chunk * 64 + wave * 16;
    float qsum = 0.f;

    for (int m = 0; m < 16; ++m) {
        const int i = ibase + m;
        const float si = s_row[i];    // LDS broadcast
        const float ti = t_row[i];
        float rsum = 0.f, hsum = 0.f;
#pragma unroll
        for (int jt = 0; jt < 6; ++jt) {
            const int j = jt * 64 + lane;
            const float sj = s_row[j];
            const float tj = t_row[j];
            const float x = sj - si;
            const float heav = (x < 0.f) ? 0.f : 1.f;
            const float e = fminf(fmaxf(-100.f * x, -50.f), 50.f);
            const float sig = 1.f / (1.f + __expf(e));
            const float posb = (x > 0.05f) ? (100.f * (x - 0.05f) + 1.44f) : (0.5f + sig);
            const float infv = (x > 0.f) ? posb : sig;
            const float stp = (ti > tj) ? infv : heav;
            const float mr = fminf(ti, tj) * (1.f / 3.f);
            const float msk = (j != i) ? 1.f : 0.f;
            rsum += msk * stp;
            hsum += msk * heav * mr;
        }
        // 64-lane butterfly reduce (both sums)
#pragma unroll
        for (int off = 32; off > 0; off >>= 1) {
            rsum += __shfl_xor(rsum, off, 64);
            hsum += __shfl_xor(hsum, off, 64);
        }
        qsum += (ti * (1.f / 3.f) + hsum) / (1.f + rsum);
    }

    if (lane == 0) qlds[wave] = qsum;
    __syncthreads();
    if (tid == 0) {
        float tot = qlds[0] + qlds[1] + qlds[2] + qlds[3];
        block_out[b * 6 + chunk] = tot / (relsum * (float)NB);
    }
}

// ---------------- Kernel 3: final reduce ----------------
__global__ __launch_bounds__(256) void hap_finalize(const float* __restrict__ block_out,
                                                    float* __restrict__ out) {
    __shared__ float red[256];
    float p = 0.f;
    for (int k = threadIdx.x; k < NB * 6; k += 256) p += block_out[k];
    red[threadIdx.x] = p;
    __syncthreads();
    for (int sft = 128; sft > 0; sft >>= 1) {
        if (threadIdx.x < sft) red[threadIdx.x] += red[threadIdx.x + sft];
        __syncthreads();
    }
    if (threadIdx.x == 0) out[0] = 1.f - red[0];
}

extern "C" void kernel_launch(void* const* d_in, const int* in_sizes, int n_in,
                              void* d_out, int out_size, void* d_ws, size_t ws_size,
                              hipStream_t stream) {
    const float* emb = (const float*)d_in[0];
    const int* labels = (const int*)d_in[1];
    float* out = (float*)d_out;

    float* s = (float*)d_ws;                 // 384*384 f32
    float* block_out = s + NB * NB;          // 2304 f32

    gemm_scores<<<dim3(12, 12), 256, 0, stream>>>(emb, s);
    hap_main<<<dim3(6, NB), 256, 0, stream>>>(s, labels, block_out);
    hap_finalize<<<1, 256, 0, stream>>>(block_out, out);
}

// Round 2
// 62.558 us; speedup vs baseline: 1.3417x; 1.3417x over previous
//
#include <hip/hip_runtime.h>
#include <hip/hip_bf16.h>

#define NB 384
#define ND 512

// ---------------- Kernel 1: scores = emb @ emb.T (f32), split-K=2 ----------
// 32x32 output tile per block, BK=64, 2x2 per-thread register tile.
// blockIdx.z selects K-half and output buffer; hap_main sums the halves.
__global__ __launch_bounds__(256) void gemm_scores(const float* __restrict__ emb,
                                                   float* __restrict__ s0,
                                                   float* __restrict__ s1) {
    __shared__ float As[32][65];
    __shared__ float Bs[32][65];
    const int tid = threadIdx.x;
    const int tx = tid & 15, ty = tid >> 4;
    const int i0 = blockIdx.y * 32, j0 = blockIdx.x * 32;
    const int kbase = blockIdx.z * (ND / 2);
    float* __restrict__ s = blockIdx.z ? s1 : s0;
    float acc00 = 0.f, acc01 = 0.f, acc10 = 0.f, acc11 = 0.f;

    for (int k0 = kbase; k0 < kbase + ND / 2; k0 += 64) {
#pragma unroll
        for (int p = 0; p < 2; ++p) {
            int idx = tid + 256 * p;
            int r = idx >> 4;
            int c = (idx & 15) << 2;
            float4 av = *reinterpret_cast<const float4*>(emb + (i0 + r) * ND + k0 + c);
            As[r][c] = av.x; As[r][c + 1] = av.y; As[r][c + 2] = av.z; As[r][c + 3] = av.w;
            float4 bv = *reinterpret_cast<const float4*>(emb + (j0 + r) * ND + k0 + c);
            Bs[r][c] = bv.x; Bs[r][c + 1] = bv.y; Bs[r][c + 2] = bv.z; Bs[r][c + 3] = bv.w;
        }
        __syncthreads();
#pragma unroll 8
        for (int kk = 0; kk < 64; ++kk) {
            float a0 = As[2 * ty][kk], a1 = As[2 * ty + 1][kk];
            float b0 = Bs[2 * tx][kk], b1 = Bs[2 * tx + 1][kk];
            acc00 = fmaf(a0, b0, acc00); acc01 = fmaf(a0, b1, acc01);
            acc10 = fmaf(a1, b0, acc10); acc11 = fmaf(a1, b1, acc11);
        }
        __syncthreads();
    }
    const int i = i0 + 2 * ty, j = j0 + 2 * tx;
    s[i * NB + j]           = acc00; s[i * NB + j + 1]       = acc01;
    s[(i + 1) * NB + j]     = acc10; s[(i + 1) * NB + j + 1] = acc11;
}

// ---------------- Kernel 2: main B^3 pass ----------------
// grid 768 = (b, i-half); 192 threads (3 waves); one thread per output row i.
// rank  = sum_all_j stp          (diagonal term == the reference's "+1")
// hrank = sum_all_j heav*min(ti,tj) / 3   (diagonal term == "+rel_i")
__global__ __launch_bounds__(192) void hap_main(const float* __restrict__ sA,
                                                const float* __restrict__ sB,
                                                const int* __restrict__ labels,
                                                float* __restrict__ block_out) {
    __shared__ float2 st[NB];          // {score, t}
    __shared__ float redT[3], redQ[3];

    const int tid = threadIdx.x;
    const int lane = tid & 63, wv = tid >> 6;
    const int b = blockIdx.x >> 1;
    const int half = blockIdx.x & 1;

    const int l0 = labels[b * 3 + 0];
    const int l1 = labels[b * 3 + 1];
    const int l2 = labels[b * 3 + 2];

    float tpart = 0.f;
    for (int j = tid; j < NB; j += 192) {
        float sv = sA[b * NB + j] + sB[b * NB + j];
        float t = (float)((labels[j * 3 + 0] == l0) +
                          (labels[j * 3 + 1] == l1) +
                          (labels[j * 3 + 2] == l2));
        st[j] = make_float2(sv, t);
        tpart += t;
    }
#pragma unroll
    for (int off = 32; off > 0; off >>= 1) tpart += __shfl_xor(tpart, off, 64);
    if (lane == 0) redT[wv] = tpart;
    __syncthreads();

    const int i = half * 192 + tid;
    const float2 sti = st[i];
    const float si = sti.x, ti = sti.y;

    float rsum = 0.f, hsum = 0.f;
#pragma unroll 4
    for (int j = 0; j < NB; ++j) {
        const float2 v = st[j];               // uniform-address LDS broadcast
        const float x = v.x - si;
        const float tj = v.y;
        // sigmoid(x/0.01) = 1/(1+exp(-100x)) = rcp(1+exp2(-144.2695*x))
        const float ex = __builtin_amdgcn_exp2f(x * -144.26950408889634f);
        const float sig = __builtin_amdgcn_rcpf(1.f + ex);
        const float posb = fmaf(100.f, x, -3.56f);      // 100*(x-0.05)+1.44
        const float sel = (x > 0.05f) ? posb : (0.5f + sig);
        const float infv = (x > 0.f) ? sel : sig;
        const float heav = (x < 0.f) ? 0.f : 1.f;
        const float stp = (ti > tj) ? infv : heav;
        rsum += stp;
        hsum += (x < 0.f) ? 0.f : fminf(ti, tj);
    }
    float q = (hsum * (1.f / 3.f)) / rsum;    // hrank/rank for row i

#pragma unroll
    for (int off = 32; off > 0; off >>= 1) q += __shfl_xor(q, off, 64);
    if (lane == 0) redQ[wv] = q;
    __syncthreads();

    if (tid == 0) {
        float qtot = redQ[0] + redQ[1] + redQ[2];
        float relsum = (redT[0] + redT[1] + redT[2]) * (1.f / 3.f);
        block_out[blockIdx.x] = qtot / (relsum * (float)NB);
    }
}

// ---------------- Kernel 3: final reduce ----------------
__global__ __launch_bounds__(256) void hap_finalize(const float* __restrict__ block_out,
                                                    float* __restrict__ out) {
    __shared__ float red[256];
    float p = 0.f;
    for (int k = threadIdx.x; k < NB * 2; k += 256) p += block_out[k];
    red[threadIdx.x] = p;
    __syncthreads();
    for (int sft = 128; sft > 0; sft >>= 1) {
        if (threadIdx.x < sft) red[threadIdx.x] += red[threadIdx.x + sft];
        __syncthreads();
    }
    if (threadIdx.x == 0) out[0] = 1.f - red[0];
}

extern "C" void kernel_launch(void* const* d_in, const int* in_sizes, int n_in,
                              void* d_out, int out_size, void* d_ws, size_t ws_size,
                              hipStream_t stream) {
    const float* emb = (const float*)d_in[0];
    const int* labels = (const int*)d_in[1];
    float* out = (float*)d_out;

    float* s0 = (float*)d_ws;                    // 384*384 f32
    float* s1 = s0 + NB * NB;                    // 384*384 f32
    float* block_out = s1 + NB * NB;             // 768 f32

    gemm_scores<<<dim3(12, 12, 2), 256, 0, stream>>>(emb, s0, s1);
    hap_main<<<dim3(NB * 2), 192, 0, stream>>>(s0, s1, labels, block_out);
    hap_finalize<<<1, 256, 0, stream>>>(block_out, out);
}

// Round 3
// 57.961 us; speedup vs baseline: 1.4481x; 1.0793x over previous
//
#include <hip/hip_runtime.h>
#include <hip/hip_bf16.h>

#define NB 384
#define ND 512

// ---------------- Kernel 1: scores = emb @ emb.T (f32), split-K=2 ----------
__global__ __launch_bounds__(256) void gemm_scores(const float* __restrict__ emb,
                                                   float* __restrict__ s0,
                                                   float* __restrict__ s1) {
    __shared__ float As[32][65];
    __shared__ float Bs[32][65];
    const int tid = threadIdx.x;
    const int tx = tid & 15, ty = tid >> 4;
    const int i0 = blockIdx.y * 32, j0 = blockIdx.x * 32;
    const int kbase = blockIdx.z * (ND / 2);
    float* __restrict__ s = blockIdx.z ? s1 : s0;
    float acc00 = 0.f, acc01 = 0.f, acc10 = 0.f, acc11 = 0.f;

    for (int k0 = kbase; k0 < kbase + ND / 2; k0 += 64) {
#pragma unroll
        for (int p = 0; p < 2; ++p) {
            int idx = tid + 256 * p;
            int r = idx >> 4;
            int c = (idx & 15) << 2;
            float4 av = *reinterpret_cast<const float4*>(emb + (i0 + r) * ND + k0 + c);
            As[r][c] = av.x; As[r][c + 1] = av.y; As[r][c + 2] = av.z; As[r][c + 3] = av.w;
            float4 bv = *reinterpret_cast<const float4*>(emb + (j0 + r) * ND + k0 + c);
            Bs[r][c] = bv.x; Bs[r][c + 1] = bv.y; Bs[r][c + 2] = bv.z; Bs[r][c + 3] = bv.w;
        }
        __syncthreads();
#pragma unroll 8
        for (int kk = 0; kk < 64; ++kk) {
            float a0 = As[2 * ty][kk], a1 = As[2 * ty + 1][kk];
            float b0 = Bs[2 * tx][kk], b1 = Bs[2 * tx + 1][kk];
            acc00 = fmaf(a0, b0, acc00); acc01 = fmaf(a0, b1, acc01);
            acc10 = fmaf(a1, b0, acc10); acc11 = fmaf(a1, b1, acc11);
        }
        __syncthreads();
    }
    const int i = i0 + 2 * ty, j = j0 + 2 * tx;
    s[i * NB + j]           = acc00; s[i * NB + j + 1]       = acc01;
    s[(i + 1) * NB + j]     = acc10; s[(i + 1) * NB + j + 1] = acc11;
}

// ---------------- Kernel 2: partial rank/hrank sums ----------------
// grid (384, 2, 2) = (b, ihalf, jhalf); 192 threads; one thread per row i,
// inner loop over a 192-wide j chunk staged in LDS.
// Diagonal needs no special case: x==0 exactly -> stp=1 ("+1"), hsum += ti ("+rel").
__global__ __launch_bounds__(192) void hap_part(const float* __restrict__ sA,
                                                const float* __restrict__ sB,
                                                const int* __restrict__ labels,
                                                float2* __restrict__ part0,
                                                float2* __restrict__ part1) {
    __shared__ alignas(16) float2 st[192];

    const int tid = threadIdx.x;
    const int b = blockIdx.x, ih = blockIdx.y, jh = blockIdx.z;

    const int l0 = labels[b * 3 + 0];
    const int l1 = labels[b * 3 + 1];
    const int l2 = labels[b * 3 + 2];

    {
        const int j = jh * 192 + tid;
        float sv = sA[b * NB + j] + sB[b * NB + j];
        float t = (float)((labels[j * 3 + 0] == l0) +
                          (labels[j * 3 + 1] == l1) +
                          (labels[j * 3 + 2] == l2));
        st[tid] = make_float2(sv, t);
    }
    const int i = ih * 192 + tid;
    const float si = sA[b * NB + i] + sB[b * NB + i];
    const float ti = (float)((labels[i * 3 + 0] == l0) +
                             (labels[i * 3 + 1] == l1) +
                             (labels[i * 3 + 2] == l2));
    __syncthreads();

    float rsum = 0.f, hsum = 0.f;
    const float4* stv = reinterpret_cast<const float4*>(st);
#pragma unroll 4
    for (int jj = 0; jj < 96; ++jj) {
        const float4 v = stv[jj];   // two {score,t} pairs, uniform-addr broadcast
        {
            const float x = v.x - si, tj = v.y;
            const float ex = __builtin_amdgcn_exp2f(x * -144.26950408889634f);
            const float sig = __builtin_amdgcn_rcpf(1.f + ex);
            const float posb = fmaf(100.f, x, -3.56f);
            const float sel = (x > 0.05f) ? posb : (0.5f + sig);
            const float infv = (x > 0.f) ? sel : sig;
            const float heav = (x < 0.f) ? 0.f : 1.f;
            rsum += (ti > tj) ? infv : heav;
            hsum += (x < 0.f) ? 0.f : fminf(ti, tj);
        }
        {
            const float x = v.z - si, tj = v.w;
            const float ex = __builtin_amdgcn_exp2f(x * -144.26950408889634f);
            const float sig = __builtin_amdgcn_rcpf(1.f + ex);
            const float posb = fmaf(100.f, x, -3.56f);
            const float sel = (x > 0.05f) ? posb : (0.5f + sig);
            const float infv = (x > 0.f) ? sel : sig;
            const float heav = (x < 0.f) ? 0.f : 1.f;
            rsum += (ti > tj) ? infv : heav;
            hsum += (x < 0.f) ? 0.f : fminf(ti, tj);
        }
    }
    float2* __restrict__ part = jh ? part1 : part0;
    part[b * NB + i] = make_float2(rsum, hsum);
}

// ---------------- Kernel 3: per-b combine ----------------
// mhap_b = sum_i (h_i / r_i) / sum_j t_j   (the /3 factors cancel)
__global__ __launch_bounds__(192) void hap_combine(const float2* __restrict__ part0,
                                                   const float2* __restrict__ part1,
                                                   const int* __restrict__ labels,
                                                   float* __restrict__ bsum) {
    __shared__ float redT[3], redQ[3];
    const int tid = threadIdx.x, lane = tid & 63, wv = tid >> 6;
    const int b = blockIdx.x;

    const int l0 = labels[b * 3 + 0];
    const int l1 = labels[b * 3 + 1];
    const int l2 = labels[b * 3 + 2];

    float tpart = 0.f;
    for (int j = tid; j < NB; j += 192)
        tpart += (float)((labels[j * 3 + 0] == l0) +
                         (labels[j * 3 + 1] == l1) +
                         (labels[j * 3 + 2] == l2));
#pragma unroll
    for (int off = 32; off > 0; off >>= 1) tpart += __shfl_xor(tpart, off, 64);
    if (lane == 0) redT[wv] = tpart;

    float qacc = 0.f;
    for (int i = tid; i < NB; i += 192) {
        const float2 p0 = part0[b * NB + i];
        const float2 p1 = part1[b * NB + i];
        qacc += (p0.y + p1.y) / (p0.x + p1.x);
    }
#pragma unroll
    for (int off = 32; off > 0; off >>= 1) qacc += __shfl_xor(qacc, off, 64);
    if (lane == 0) redQ[wv] = qacc;
    __syncthreads();

    if (tid == 0) {
        const float tsum = redT[0] + redT[1] + redT[2];   // = 3 * relsum
        const float qtot = redQ[0] + redQ[1] + redQ[2];   // = sum h/r
        bsum[b] = qtot / (tsum * (float)NB);
    }
}

// ---------------- Kernel 4: final reduce ----------------
__global__ __launch_bounds__(64) void hap_final(const float* __restrict__ bsum,
                                                float* __restrict__ out) {
    const int tid = threadIdx.x;
    float p = 0.f;
    for (int k = tid; k < NB; k += 64) p += bsum[k];
#pragma unroll
    for (int off = 32; off > 0; off >>= 1) p += __shfl_xor(p, off, 64);
    if (tid == 0) out[0] = 1.f - p;
}

extern "C" void kernel_launch(void* const* d_in, const int* in_sizes, int n_in,
                              void* d_out, int out_size, void* d_ws, size_t ws_size,
                              hipStream_t stream) {
    const float* emb = (const float*)d_in[0];
    const int* labels = (const int*)d_in[1];
    float* out = (float*)d_out;

    float* s0 = (float*)d_ws;                        // 147456 f32
    float* s1 = s0 + NB * NB;                        // 147456 f32
    float2* part0 = (float2*)(s1 + NB * NB);         // 147456 float2
    float2* part1 = part0 + NB * NB;                 // 147456 float2
    float* bsum = (float*)(part1 + NB * NB);         // 384 f32

    gemm_scores<<<dim3(12, 12, 2), 256, 0, stream>>>(emb, s0, s1);
    hap_part<<<dim3(NB, 2, 2), 192, 0, stream>>>(s0, s1, labels, part0, part1);
    hap_combine<<<NB, 192, 0, stream>>>(part0, part1, labels, bsum);
    hap_final<<<1, 64, 0, stream>>>(bsum, out);
}

// Round 4
// 44.802 us; speedup vs baseline: 1.8735x; 1.2937x over previous
//
#include <hip/hip_runtime.h>
#include <hip/hip_bf16.h>

#define NB 384
#define ND 512

// ---------------- Kernel 1: scores = emb @ emb.T (f32), split-K=2 ----------
__global__ __launch_bounds__(256) void gemm_scores(const float* __restrict__ emb,
                                                   float* __restrict__ s0,
                                                   float* __restrict__ s1) {
    __shared__ float As[32][65];
    __shared__ float Bs[32][65];
    const int tid = threadIdx.x;
    const int tx = tid & 15, ty = tid >> 4;
    const int i0 = blockIdx.y * 32, j0 = blockIdx.x * 32;
    const int kbase = blockIdx.z * (ND / 2);
    float* __restrict__ s = blockIdx.z ? s1 : s0;
    float acc00 = 0.f, acc01 = 0.f, acc10 = 0.f, acc11 = 0.f;

    for (int k0 = kbase; k0 < kbase + ND / 2; k0 += 64) {
#pragma unroll
        for (int p = 0; p < 2; ++p) {
            int idx = tid + 256 * p;
            int r = idx >> 4;
            int c = (idx & 15) << 2;
            float4 av = *reinterpret_cast<const float4*>(emb + (i0 + r) * ND + k0 + c);
            As[r][c] = av.x; As[r][c + 1] = av.y; As[r][c + 2] = av.z; As[r][c + 3] = av.w;
            float4 bv = *reinterpret_cast<const float4*>(emb + (j0 + r) * ND + k0 + c);
            Bs[r][c] = bv.x; Bs[r][c + 1] = bv.y; Bs[r][c + 2] = bv.z; Bs[r][c + 3] = bv.w;
        }
        __syncthreads();
#pragma unroll 8
        for (int kk = 0; kk < 64; ++kk) {
            float a0 = As[2 * ty][kk], a1 = As[2 * ty + 1][kk];
            float b0 = Bs[2 * tx][kk], b1 = Bs[2 * tx + 1][kk];
            acc00 = fmaf(a0, b0, acc00); acc01 = fmaf(a0, b1, acc01);
            acc10 = fmaf(a1, b0, acc10); acc11 = fmaf(a1, b1, acc11);
        }
        __syncthreads();
    }
    const int i = i0 + 2 * ty, j = j0 + 2 * tx;
    s[i * NB + j]           = acc00; s[i * NB + j + 1]       = acc01;
    s[(i + 1) * NB + j]     = acc10; s[(i + 1) * NB + j + 1] = acc11;
}

// ---------------- Kernel 2: prep — sum K-halves, group scores by t-class ---
// One block per b, 384 threads (one per j). Class grouping is an exact
// permutation; sums over j are order-free so no un-permute is ever needed.
__global__ __launch_bounds__(NB) void hap_prep(const float* __restrict__ s0,
                                               const float* __restrict__ s1,
                                               const int* __restrict__ labels,
                                               float* __restrict__ g,
                                               int* __restrict__ offs,
                                               float* __restrict__ tsumArr) {
    __shared__ int wcnt[6][4];
    __shared__ int wbase[6][4];
    __shared__ int cbase[4];
    const int tid = threadIdx.x, lane = tid & 63, wv = tid >> 6;
    const int b = blockIdx.x;
    const int l0 = labels[b * 3 + 0], l1 = labels[b * 3 + 1], l2 = labels[b * 3 + 2];
    const int t = (labels[tid * 3 + 0] == l0) + (labels[tid * 3 + 1] == l1) +
                  (labels[tid * 3 + 2] == l2);
    const float sv = s0[b * NB + tid] + s1[b * NB + tid];
    const unsigned long long mlt = (1ull << lane) - 1ull;
    int myrank = 0;
#pragma unroll
    for (int c = 0; c < 4; ++c) {
        unsigned long long m = __ballot(t == c);
        if (t == c) myrank = __popcll(m & mlt);
        if (lane == 0) wcnt[wv][c] = __popcll(m);
    }
    __syncthreads();
    if (tid == 0) {
        int tot0 = 0, tot1 = 0, tot2 = 0, tot3 = 0;
        for (int w = 0; w < 6; ++w) {
            wbase[w][0] = tot0; tot0 += wcnt[w][0];
            wbase[w][1] = tot1; tot1 += wcnt[w][1];
            wbase[w][2] = tot2; tot2 += wcnt[w][2];
            wbase[w][3] = tot3; tot3 += wcnt[w][3];
        }
        cbase[0] = 0; cbase[1] = tot0; cbase[2] = tot0 + tot1; cbase[3] = tot0 + tot1 + tot2;
        offs[b * 4 + 0] = cbase[1];          // start of class 1
        offs[b * 4 + 1] = cbase[2];          // start of class 2
        offs[b * 4 + 2] = cbase[3];          // start of class 3
        tsumArr[b] = (float)(tot1 + 2 * tot2 + 3 * tot3);
    }
    __syncthreads();
    g[b * NB + cbase[t] + wbase[wv][t] + myrank] = sv;
}

// ---------------- Kernel 3: segmented rank/hrank partials ----------------
// grid (b, ihalf, jhalf); 192 threads; i,j indices are GROUPED positions.
// Per class-run c: if ti > c (inferior)  -> sigmoid sum + count
//                  else                  -> count only (pure heaviside)
// Diagonal handled implicitly: j==i lies in run c==ti -> count branch,
// sj==si counts 1 into rsum ("+1") and ti*1 into hsum ("+rel*3").
__global__ __launch_bounds__(192) void hap_part(const float* __restrict__ g,
                                                const int* __restrict__ offs,
                                                float2* __restrict__ part) {
    __shared__ alignas(16) float gs[192];
    const int tid = threadIdx.x;
    const int b = blockIdx.x, ih = blockIdx.y, jh = blockIdx.z;
    const int w0 = jh * 192;

    gs[tid] = g[b * NB + w0 + tid];
    const int i = ih * 192 + tid;
    const float si = g[b * NB + i];
    const int S1 = offs[b * 4 + 0], S2 = offs[b * 4 + 1], S3 = offs[b * 4 + 2];
    const int ti = (i >= S1) + (i >= S2) + (i >= S3);
    __syncthreads();

    const int R[5] = {0, S1, S2, S3, NB};
    const float siK = si * -144.26950408889634f;
    const float pconst = fmaf(-100.f, si, -3.56f);   // posb = 100*sj + pconst
    const float c1 = si + 0.05f;

    float rsum = 0.f, hsum = 0.f;
#pragma unroll
    for (int c = 0; c < 4; ++c) {
        int lo = (R[c] > w0 ? R[c] : w0) - w0;
        int hi = (R[c + 1] < w0 + 192 ? R[c + 1] : w0 + 192) - w0;
        if (lo >= hi) continue;
        if (ti > c) {
            float rs = 0.f; int cnt = 0;
#pragma unroll 2
            for (int k = lo; k < hi; ++k) {
                const float sj = gs[k];
                const float ex = __builtin_amdgcn_exp2f(fmaf(sj, -144.26950408889634f, -siK));
                const float sg = __builtin_amdgcn_rcpf(1.f + ex);
                const float posb = fmaf(100.f, sj, pconst);
                const float sel = (sj > c1) ? posb : (0.5f + sg);
                rs += (sj > si) ? sel : sg;
                cnt += (sj >= si);
            }
            rsum += rs; hsum += (float)(c * cnt);
        } else {
            int cnt = 0;
            int k = lo;
            for (; k < hi && (k & 3); ++k) cnt += (gs[k] >= si);
            for (; k + 4 <= hi; k += 4) {
                const float4 v = *reinterpret_cast<const float4*>(&gs[k]);
                cnt += (v.x >= si) + (v.y >= si) + (v.z >= si) + (v.w >= si);
            }
            for (; k < hi; ++k) cnt += (gs[k] >= si);
            rsum += (float)cnt; hsum += (float)(ti * cnt);
        }
    }
    part[jh * (NB * NB) + b * NB + i] = make_float2(rsum, hsum);
}

// ---------------- Kernel 4: per-b combine ----------------
// mhap_b = sum_i (h_i / r_i) / sum_j t_j     (the /3's cancel)
__global__ __launch_bounds__(192) void hap_combine(const float2* __restrict__ part,
                                                   const float* __restrict__ tsumArr,
                                                   float* __restrict__ bsum) {
    __shared__ float redQ[3];
    const int tid = threadIdx.x, lane = tid & 63, wv = tid >> 6;
    const int b = blockIdx.x;
    float q = 0.f;
#pragma unroll
    for (int rep = 0; rep < 2; ++rep) {
        const int i = rep * 192 + tid;
        const float2 p0 = part[b * NB + i];
        const float2 p1 = part[NB * NB + b * NB + i];
        q += (p0.y + p1.y) / (p0.x + p1.x);
    }
#pragma unroll
    for (int off = 32; off > 0; off >>= 1) q += __shfl_xor(q, off, 64);
    if (lane == 0) redQ[wv] = q;
    __syncthreads();
    if (tid == 0) bsum[b] = (redQ[0] + redQ[1] + redQ[2]) / (tsumArr[b] * (float)NB);
}

// ---------------- Kernel 5: final reduce ----------------
__global__ __launch_bounds__(64) void hap_final(const float* __restrict__ bsum,
                                                float* __restrict__ out) {
    const int tid = threadIdx.x;
    float p = 0.f;
    for (int k = tid; k < NB; k += 64) p += bsum[k];
#pragma unroll
    for (int off = 32; off > 0; off >>= 1) p += __shfl_xor(p, off, 64);
    if (tid == 0) out[0] = 1.f - p;
}

extern "C" void kernel_launch(void* const* d_in, const int* in_sizes, int n_in,
                              void* d_out, int out_size, void* d_ws, size_t ws_size,
                              hipStream_t stream) {
    const float* emb = (const float*)d_in[0];
    const int* labels = (const int*)d_in[1];
    float* out = (float*)d_out;

    float* s0 = (float*)d_ws;                    // 147456 f32
    float* s1 = s0 + NB * NB;                    // 147456 f32
    float* g  = s1 + NB * NB;                    // 147456 f32 (grouped scores)
    float2* part = (float2*)(g + NB * NB);       // 2 * 147456 float2
    int* offs = (int*)(part + 2 * NB * NB);      // 384*4 int
    float* tsumArr = (float*)(offs + NB * 4);    // 384 f32
    float* bsum = tsumArr + NB;                  // 384 f32

    gemm_scores<<<dim3(12, 12, 2), 256, 0, stream>>>(emb, s0, s1);
    hap_prep<<<NB, NB, 0, stream>>>(s0, s1, labels, g, offs, tsumArr);
    hap_part<<<dim3(NB, 2, 2), 192, 0, stream>>>(g, offs, part);
    hap_combine<<<NB, 192, 0, stream>>>(part, tsumArr, bsum);
    hap_final<<<1, 64, 0, stream>>>(bsum, out);
}

// Round 5
// 44.314 us; speedup vs baseline: 1.8941x; 1.0110x over previous
//
#include <hip/hip_runtime.h>
#include <hip/hip_bf16.h>

#define NB 384
#define ND 512

// ---------------- Kernel 1: scores = emb @ emb.T (f32), split-K=2 ----------
__global__ __launch_bounds__(256) void gemm_scores(const float* __restrict__ emb,
                                                   float* __restrict__ s0,
                                                   float* __restrict__ s1) {
    __shared__ float As[32][65];
    __shared__ float Bs[32][65];
    const int tid = threadIdx.x;
    const int tx = tid & 15, ty = tid >> 4;
    const int i0 = blockIdx.y * 32, j0 = blockIdx.x * 32;
    const int kbase = blockIdx.z * (ND / 2);
    float* __restrict__ s = blockIdx.z ? s1 : s0;
    float acc00 = 0.f, acc01 = 0.f, acc10 = 0.f, acc11 = 0.f;

    for (int k0 = kbase; k0 < kbase + ND / 2; k0 += 64) {
#pragma unroll
        for (int p = 0; p < 2; ++p) {
            int idx = tid + 256 * p;
            int r = idx >> 4;
            int c = (idx & 15) << 2;
            float4 av = *reinterpret_cast<const float4*>(emb + (i0 + r) * ND + k0 + c);
            As[r][c] = av.x; As[r][c + 1] = av.y; As[r][c + 2] = av.z; As[r][c + 3] = av.w;
            float4 bv = *reinterpret_cast<const float4*>(emb + (j0 + r) * ND + k0 + c);
            Bs[r][c] = bv.x; Bs[r][c + 1] = bv.y; Bs[r][c + 2] = bv.z; Bs[r][c + 3] = bv.w;
        }
        __syncthreads();
#pragma unroll 8
        for (int kk = 0; kk < 64; ++kk) {
            float a0 = As[2 * ty][kk], a1 = As[2 * ty + 1][kk];
            float b0 = Bs[2 * tx][kk], b1 = Bs[2 * tx + 1][kk];
            acc00 = fmaf(a0, b0, acc00); acc01 = fmaf(a0, b1, acc01);
            acc10 = fmaf(a1, b0, acc10); acc11 = fmaf(a1, b1, acc11);
        }
        __syncthreads();
    }
    const int i = i0 + 2 * ty, j = j0 + 2 * tx;
    s[i * NB + j]           = acc00; s[i * NB + j + 1]       = acc01;
    s[(i + 1) * NB + j]     = acc10; s[(i + 1) * NB + j + 1] = acc11;
}

// Sigmoid-run helper: sum step values over grouped run [lo,hi); optionally
// count heaviside hits (not needed for class 0 since min(ti,0)==0).
template <bool NEED_CNT>
__device__ __forceinline__ void sig_run(const float* __restrict__ gs, int lo, int hi,
                                        float si, float siK, float pconst, float c1,
                                        float& rsum, int& cnt) {
#pragma unroll 2
    for (int k = lo; k < hi; ++k) {
        const float sj = gs[k];
        const float ex = __builtin_amdgcn_exp2f(fmaf(sj, -144.26950408889634f, -siK));
        const float sg = __builtin_amdgcn_rcpf(1.f + ex);
        const float posb = fmaf(100.f, sj, pconst);
        const float sel = (sj > c1) ? posb : (0.5f + sg);
        rsum += (sj > si) ? sel : sg;
        if (NEED_CNT) cnt += (sj >= si);
    }
}

// ---------------- Kernel 2: fused group + rank/hrank + per-block reduce ----
// grid (384, 2) = (b, ihalf); 192 threads (3 waves).
// Stage score row b grouped by relevance class t(j) in LDS (exact permutation;
// all j-sums are order-free). Then thread tid handles grouped row index
// i = ihalf*192+tid: classes c < ti take the sigmoid path, the contiguous
// tail [R[ti], NB) is a pure heaviside count. Diagonal handled implicitly
// (x==0 in the count path -> +1 rank, +ti hsum).
__global__ __launch_bounds__(192) void hap_fused(const float* __restrict__ s0,
                                                 const float* __restrict__ s1,
                                                 const int* __restrict__ labels,
                                                 float* __restrict__ bpart) {
    __shared__ alignas(16) float gs[NB];
    __shared__ int wcnt[6][4];
    __shared__ int wbase[6][4];
    __shared__ int cbase[5];
    __shared__ float tsum_sh;
    __shared__ float redQ[3];

    const int tid = threadIdx.x, lane = tid & 63, wv = tid >> 6;
    const int b = blockIdx.x, ih = blockIdx.y;

    const int l0 = labels[b * 3 + 0], l1 = labels[b * 3 + 1], l2 = labels[b * 3 + 2];

    // two grouping passes: jA = tid, jB = tid + 192
    const int jA = tid, jB = tid + 192;
    const int tA = (labels[jA * 3 + 0] == l0) + (labels[jA * 3 + 1] == l1) +
                   (labels[jA * 3 + 2] == l2);
    const int tB = (labels[jB * 3 + 0] == l0) + (labels[jB * 3 + 1] == l1) +
                   (labels[jB * 3 + 2] == l2);
    const float svA = s0[b * NB + jA] + s1[b * NB + jA];
    const float svB = s0[b * NB + jB] + s1[b * NB + jB];

    const unsigned long long mlt = (1ull << lane) - 1ull;
    int rkA = 0, rkB = 0;
#pragma unroll
    for (int c = 0; c < 4; ++c) {
        unsigned long long mA = __ballot(tA == c);
        unsigned long long mB = __ballot(tB == c);
        if (tA == c) rkA = __popcll(mA & mlt);
        if (tB == c) rkB = __popcll(mB & mlt);
        if (lane == 0) { wcnt[wv][c] = __popcll(mA); wcnt[3 + wv][c] = __popcll(mB); }
    }
    __syncthreads();
    if (tid == 0) {
        int tot0 = 0, tot1 = 0, tot2 = 0, tot3 = 0;
        for (int w = 0; w < 6; ++w) {
            wbase[w][0] = tot0; tot0 += wcnt[w][0];
            wbase[w][1] = tot1; tot1 += wcnt[w][1];
            wbase[w][2] = tot2; tot2 += wcnt[w][2];
            wbase[w][3] = tot3; tot3 += wcnt[w][3];
        }
        cbase[0] = 0; cbase[1] = tot0; cbase[2] = tot0 + tot1;
        cbase[3] = tot0 + tot1 + tot2; cbase[4] = NB;
        tsum_sh = (float)(tot1 + 2 * tot2 + 3 * tot3);
    }
    __syncthreads();
    gs[cbase[tA] + wbase[wv][tA] + rkA] = svA;
    gs[cbase[tB] + wbase[3 + wv][tB] + rkB] = svB;
    __syncthreads();

    const int S1 = cbase[1], S2 = cbase[2], S3 = cbase[3];
    const int i = ih * 192 + tid;
    const float si = gs[i];
    const int ti = (i >= S1) + (i >= S2) + (i >= S3);
    const float siK = si * -144.26950408889634f;
    const float pconst = fmaf(-100.f, si, -3.56f);   // posb = 100*sj + pconst
    const float c1 = si + 0.05f;

    float rsum = 0.f, hsum = 0.f;
    int cnt = 0;
    // inferior class runs (c < ti): sigmoid path
    if (ti > 0) {                       // c = 0: min(ti,0)==0 -> no count needed
        sig_run<false>(gs, 0, S1, si, siK, pconst, c1, rsum, cnt);
    }
    if (ti > 1) {                       // c = 1
        int c1n = 0;
        sig_run<true>(gs, S1, S2, si, siK, pconst, c1, rsum, c1n);
        hsum += (float)c1n;
    }
    if (ti > 2) {                       // c = 2
        int c2n = 0;
        sig_run<true>(gs, S2, S3, si, siK, pconst, c1, rsum, c2n);
        hsum += (float)(2 * c2n);
    }
    // non-inferior tail [R[ti], NB): pure heaviside count; min(ti,tj) == ti
    {
        const int lo = cbase[ti];
        int k = lo, hcnt = 0;
        for (; k < NB && (k & 3); ++k) hcnt += (gs[k] >= si);
        for (; k + 4 <= NB; k += 4) {
            const float4 v = *reinterpret_cast<const float4*>(&gs[k]);
            hcnt += (v.x >= si) + (v.y >= si) + (v.z >= si) + (v.w >= si);
        }
        rsum += (float)hcnt;
        hsum += (float)(ti * hcnt);
    }

    float q = hsum / rsum;
#pragma unroll
    for (int off = 32; off > 0; off >>= 1) q += __shfl_xor(q, off, 64);
    if (lane == 0) redQ[wv] = q;
    __syncthreads();
    if (tid == 0)
        bpart[b * 2 + ih] = (redQ[0] + redQ[1] + redQ[2]) / (tsum_sh * (float)NB);
}

// ---------------- Kernel 3: final reduce over 768 block partials ----------
__global__ __launch_bounds__(64) void hap_final(const float* __restrict__ bpart,
                                                float* __restrict__ out) {
    const int tid = threadIdx.x;
    float p = 0.f;
    for (int k = tid; k < NB * 2; k += 64) p += bpart[k];
#pragma unroll
    for (int off = 32; off > 0; off >>= 1) p += __shfl_xor(p, off, 64);
    if (tid == 0) out[0] = 1.f - p;
}

extern "C" void kernel_launch(void* const* d_in, const int* in_sizes, int n_in,
                              void* d_out, int out_size, void* d_ws, size_t ws_size,
                              hipStream_t stream) {
    const float* emb = (const float*)d_in[0];
    const int* labels = (const int*)d_in[1];
    float* out = (float*)d_out;

    float* s0 = (float*)d_ws;                    // 147456 f32
    float* s1 = s0 + NB * NB;                    // 147456 f32
    float* bpart = s1 + NB * NB;                 // 768 f32

    gemm_scores<<<dim3(12, 12, 2), 256, 0, stream>>>(emb, s0, s1);
    hap_fused<<<dim3(NB, 2), 192, 0, stream>>>(s0, s1, labels, bpart);
    hap_final<<<1, 64, 0, stream>>>(bpart, out);
}